// Round 1
// baseline (1217.726 us; speedup 1.0000x reference)
//
#include <hip/hip_runtime.h>
#include <math.h>

// Problem constants
#define NB   2
#define CC   256
#define HH   128
#define WW   128
#define NHD  8
#define PP   4
#define DHD  32
#define HPP  130
#define WPP  130
#define LQ   16384   // HH*WW

// -------------------------------------------------------------------------
// Kernel 1: fused depthwise 7x7 conv + bias + channel-LayerNorm + exact GELU
// One block per spatial position (n,h,w); 256 threads = channels.
// -------------------------------------------------------------------------
__global__ __launch_bounds__(256) void conv_ln_gelu_kernel(
    const float* __restrict__ q,      // (N, LQ, C)
    const float* __restrict__ kern,   // (C, 1, 7, 7) -> (C,49)
    const float* __restrict__ kbias,  // (C)
    const float* __restrict__ lnw,    // (C)
    const float* __restrict__ lnb,    // (C)
    float* __restrict__ qact)         // (N, LQ, C)
{
    int pos = blockIdx.x;             // n*H*W + h*W + w
    int c   = threadIdx.x;
    int n   = pos >> 14;              // / (128*128)
    int hw  = pos & 16383;
    int h   = hw >> 7;
    int w   = hw & 127;

    const float* qn = q + (size_t)n * LQ * CC;
    float acc = kbias[c];
    #pragma unroll
    for (int ky = 0; ky < 7; ++ky) {
        int iy = h + ky - 3;
        if (iy < 0 || iy >= HH) continue;
        #pragma unroll
        for (int kx = 0; kx < 7; ++kx) {
            int ix = w + kx - 3;
            if (ix < 0 || ix >= WW) continue;
            acc += qn[((size_t)iy * WW + ix) * CC + c] * kern[c * 49 + ky * 7 + kx];
        }
    }

    // LayerNorm across 256 channels (block reduce)
    __shared__ float2 red[256];
    red[c] = make_float2(acc, acc * acc);
    __syncthreads();
    #pragma unroll
    for (int s = 128; s > 0; s >>= 1) {
        if (c < s) {
            red[c].x += red[c + s].x;
            red[c].y += red[c + s].y;
        }
        __syncthreads();
    }
    float mu  = red[0].x * (1.0f / 256.0f);
    float var = red[0].y * (1.0f / 256.0f) - mu * mu;
    float inv = rsqrtf(var + 1e-5f);
    float yv  = (acc - mu) * inv * lnw[c] + lnb[c];
    // exact GELU: x * 0.5 * (1 + erf(x/sqrt(2)))
    float g = 0.5f * yv * (1.0f + erff(yv * 0.7071067811865475f));
    qact[(size_t)pos * CC + c] = g;
}

// -------------------------------------------------------------------------
// Kernel 2: tiled fp32 GEMM  C = A(MxK) * B(KxN) + bias
// BM=64, BN=64, BK=16, 256 threads, 4x4 microtile.
// MODE 0: plain row-major store (stride Nn)
// MODE 1: store into padded value layout (N, HP, WP, C) at (h+1, w+1)
// -------------------------------------------------------------------------
#define BM 64
#define BN 64
#define BK 16

template <int MODE>
__global__ __launch_bounds__(256) void gemm_tiled(
    const float* __restrict__ A,
    const float* __restrict__ B,
    const float* __restrict__ bias,
    float* __restrict__ Cout,
    int M, int Nn, int K)
{
    __shared__ float As[BK][BM];
    __shared__ float Bs[BK][BN];

    int tid = threadIdx.x;
    int bm  = blockIdx.x * BM;
    int bn  = blockIdx.y * BN;
    int ty  = tid >> 4;   // 0..15
    int tx  = tid & 15;   // 0..15

    // A load mapping: thread -> row = tid/4, 4 contiguous k at (tid%4)*4
    int arow = tid >> 2;
    int ak   = (tid & 3) * 4;
    // B load mapping: thread -> k-row = tid/16, 4 contiguous cols at (tid%16)*4
    int brow = tid >> 4;
    int bcol = (tid & 15) * 4;

    float acc[4][4] = {};

    for (int k0 = 0; k0 < K; k0 += BK) {
        float4 av = *reinterpret_cast<const float4*>(
            &A[(size_t)(bm + arow) * K + k0 + ak]);
        As[ak + 0][arow] = av.x;
        As[ak + 1][arow] = av.y;
        As[ak + 2][arow] = av.z;
        As[ak + 3][arow] = av.w;

        float4 bv;
        if (bn + bcol < Nn)
            bv = *reinterpret_cast<const float4*>(
                &B[(size_t)(k0 + brow) * Nn + bn + bcol]);
        else
            bv = make_float4(0.f, 0.f, 0.f, 0.f);
        *reinterpret_cast<float4*>(&Bs[brow][bcol]) = bv;

        __syncthreads();
        #pragma unroll
        for (int k = 0; k < BK; ++k) {
            float4 a4 = *reinterpret_cast<const float4*>(&As[k][ty * 4]);
            float4 b4 = *reinterpret_cast<const float4*>(&Bs[k][tx * 4]);
            float aa[4] = {a4.x, a4.y, a4.z, a4.w};
            float bb[4] = {b4.x, b4.y, b4.z, b4.w};
            #pragma unroll
            for (int i = 0; i < 4; ++i)
                #pragma unroll
                for (int j = 0; j < 4; ++j)
                    acc[i][j] += aa[i] * bb[j];
        }
        __syncthreads();
    }

    int row0 = bm + ty * 4;
    int col0 = bn + tx * 4;
    if (col0 >= Nn) return;
    float4 bias4 = *reinterpret_cast<const float4*>(&bias[col0]);

    #pragma unroll
    for (int i = 0; i < 4; ++i) {
        int row = row0 + i;
        float4 o;
        o.x = acc[i][0] + bias4.x;
        o.y = acc[i][1] + bias4.y;
        o.z = acc[i][2] + bias4.z;
        o.w = acc[i][3] + bias4.w;
        if (MODE == 0) {
            *reinterpret_cast<float4*>(&Cout[(size_t)row * Nn + col0]) = o;
        } else {
            // padded value store: row = n*LQ + h*W + w  ->  (n, h+1, w+1)
            int n  = row >> 14;
            int hw = row & 16383;
            int h  = hw >> 7;
            int w  = hw & 127;
            size_t dst = (((size_t)n * HPP + (h + 1)) * WPP + (w + 1)) * CC + col0;
            *reinterpret_cast<float4*>(&Cout[dst]) = o;
        }
    }
}

// -------------------------------------------------------------------------
// Kernel 3: deformable bilinear sampling + attention-weighted sum
// One block per (n,l); 256 threads = output channels (head = c/32).
// -------------------------------------------------------------------------
__global__ __launch_bounds__(256) void sampler_kernel(
    const float* __restrict__ rp,     // (N, LQ, 1, 2)
    const float* __restrict__ offb,   // (N*LQ, 64) raw offsets
    const float* __restrict__ attnb,  // (N*LQ, 32) raw logits
    const float* __restrict__ vpad,   // (N, HP, WP, C)
    float* __restrict__ outb)         // (N*LQ, C)
{
    int row  = blockIdx.x;            // n*LQ + l
    int c    = threadIdx.x;
    int n    = row >> 14;
    int head = c >> 5;

    float ref0 = rp[(size_t)row * 2 + 0];
    float ref1 = rp[(size_t)row * 2 + 1];

    // grid points p: (ky,kx) = (0,0),(0,1),(1,0),(1,1); x uses ky, y uses kx
    const float GY[4] = {0.f, 0.f, 1.f, 1.f};
    const float GX[4] = {0.f, 1.f, 0.f, 1.f};

    const float* vbase = vpad + (size_t)n * HPP * WPP * CC;
    float acc = 0.f;

    #pragma unroll
    for (int p = 0; p < 4; ++p) {
        float o0 = offb[(size_t)row * 64 + head * 8 + p * 2 + 0];
        float o1 = offb[(size_t)row * 64 + head * 8 + p * 2 + 1];
        float al = attnb[(size_t)row * 32 + head * 4 + p];
        float a  = 1.0f / (1.0f + expf(-al));

        float x = ref0 * WPP + GY[p] + o0 - 0.5f;
        float y = ref1 * HPP + GX[p] + o1 - 0.5f;

        float x0f = floorf(x), y0f = floorf(y);
        int   x0  = (int)x0f,  y0  = (int)y0f;
        float wx1 = x - x0f, wx0 = 1.f - wx1;
        float wy1 = y - y0f, wy0 = 1.f - wy1;

        float s = 0.f;
        {
            int xi = x0, yi = y0;
            if (xi >= 0 && xi < WPP && yi >= 0 && yi < HPP)
                s += wx0 * wy0 * vbase[((size_t)yi * WPP + xi) * CC + c];
        }
        {
            int xi = x0 + 1, yi = y0;
            if (xi >= 0 && xi < WPP && yi >= 0 && yi < HPP)
                s += wx1 * wy0 * vbase[((size_t)yi * WPP + xi) * CC + c];
        }
        {
            int xi = x0, yi = y0 + 1;
            if (xi >= 0 && xi < WPP && yi >= 0 && yi < HPP)
                s += wx0 * wy1 * vbase[((size_t)yi * WPP + xi) * CC + c];
        }
        {
            int xi = x0 + 1, yi = y0 + 1;
            if (xi >= 0 && xi < WPP && yi >= 0 && yi < HPP)
                s += wx1 * wy1 * vbase[((size_t)yi * WPP + xi) * CC + c];
        }
        acc += a * s;
    }
    outb[(size_t)row * CC + c] = acc;
}

// -------------------------------------------------------------------------
extern "C" void kernel_launch(void* const* d_in, const int* in_sizes, int n_in,
                              void* d_out, int out_size, void* d_ws, size_t ws_size,
                              hipStream_t stream)
{
    const float* query = (const float*)d_in[0];
    const float* rp    = (const float*)d_in[1];
    // d_in[2] input_spatial_shapes (int), d_in[3] level_start_index (int): unused
    const float* dwk   = (const float*)d_in[4];
    const float* dwb   = (const float*)d_in[5];
    const float* lnw   = (const float*)d_in[6];
    const float* lnb   = (const float*)d_in[7];
    const float* Woff  = (const float*)d_in[8];
    const float* boff  = (const float*)d_in[9];
    const float* Wattn = (const float*)d_in[10];
    const float* battn = (const float*)d_in[11];
    const float* Wval  = (const float*)d_in[12];
    const float* bval  = (const float*)d_in[13];
    const float* Wout  = (const float*)d_in[14];
    const float* bout  = (const float*)d_in[15];
    float* out = (float*)d_out;

    const int M = NB * LQ;  // 32768

    // workspace layout (floats)
    float* q_act    = (float*)d_ws;                       //  8,388,608
    float* v_pad    = q_act + (size_t)M * CC;             //  8,652,800
    float* offb     = v_pad + (size_t)NB * HPP * WPP * CC; // 2,097,152
    float* attnb    = offb + (size_t)M * 64;              //  1,048,576
    float* out_attn = q_act;  // alias: q_act dead after attn GEMM

    // zero padded value buffer (borders must be 0)
    hipMemsetAsync(v_pad, 0, (size_t)NB * HPP * WPP * CC * sizeof(float), stream);

    // 1) conv + LN + GELU
    conv_ln_gelu_kernel<<<NB * HH * WW, 256, 0, stream>>>(
        query, dwk, dwb, lnw, lnb, q_act);

    // 2) value GEMM -> padded layout
    {
        dim3 grid(M / BM, CC / BN);
        gemm_tiled<1><<<grid, 256, 0, stream>>>(q_act, Wval, bval, v_pad, M, CC, CC);
    }
    // 3) offsets GEMM (N=64)
    {
        dim3 grid(M / BM, 1);
        gemm_tiled<0><<<grid, 256, 0, stream>>>(q_act, Woff, boff, offb, M, 64, CC);
    }
    // 4) attn logits GEMM (N=32)
    {
        dim3 grid(M / BM, 1);
        gemm_tiled<0><<<grid, 256, 0, stream>>>(q_act, Wattn, battn, attnb, M, 32, CC);
    }
    // 5) sampling + weighted sum
    sampler_kernel<<<M, 256, 0, stream>>>(rp, offb, attnb, v_pad, out_attn);

    // 6) output GEMM
    {
        dim3 grid(M / BM, CC / BN);
        gemm_tiled<0><<<grid, 256, 0, stream>>>(out_attn, Wout, bout, out, M, CC, CC);
    }
}

// Round 2
// 330.460 us; speedup vs baseline: 3.6849x; 3.6849x over previous
//
#include <hip/hip_runtime.h>
#include <math.h>

// Problem constants
#define NB   2
#define CC   256
#define HH   128
#define WW   128
#define NHD  8
#define PP   4
#define DHD  32
#define HPP  130
#define WPP  130
#define LQ   16384   // HH*WW

// -------------------------------------------------------------------------
// Kernel 0: transpose depthwise weights (C,49) -> (49,C) for coalesced loads
// -------------------------------------------------------------------------
__global__ __launch_bounds__(256) void transpose_w_kernel(
    const float* __restrict__ kern,   // (C, 49)
    float* __restrict__ kt)           // (49, C)
{
    int c = threadIdx.x;              // 0..255
    int k = blockIdx.x;               // 0..48
    kt[k * CC + c] = kern[c * 49 + k];
}

// -------------------------------------------------------------------------
// Kernel 1: fused depthwise 7x7 conv + bias + channel-LayerNorm + exact GELU
// Block = one (n, h) row segment of 8 w-positions; 256 threads = channels.
// Each thread computes 8 outputs along w with register-blocked input reuse.
// -------------------------------------------------------------------------
__global__ __launch_bounds__(256) void conv_ln_gelu_kernel(
    const float* __restrict__ q,      // (N, LQ, C)
    const float* __restrict__ kt,     // (49, C) transposed weights
    const float* __restrict__ kbias,  // (C)
    const float* __restrict__ lnw,    // (C)
    const float* __restrict__ lnb,    // (C)
    float* __restrict__ qact)         // (N, LQ, C)
{
    int c  = threadIdx.x;
    int w0 = blockIdx.x * 8;          // 16 tiles across W=128
    int h  = blockIdx.y;
    int n  = blockIdx.z;

    const float* qn = q + (size_t)n * LQ * CC;

    float bias = kbias[c];
    float acc[8];
    #pragma unroll
    for (int i = 0; i < 8; ++i) acc[i] = bias;

    #pragma unroll
    for (int ky = 0; ky < 7; ++ky) {
        int iy = h + ky - 3;
        if (iy < 0 || iy >= HH) continue;

        // coalesced weight row (7 values for this thread's channel)
        float wt[7];
        #pragma unroll
        for (int kx = 0; kx < 7; ++kx)
            wt[kx] = kt[(ky * 7 + kx) * CC + c];

        // 14 input values along w (coalesced across lanes: lane = channel)
        float in[14];
        const float* qrow = qn + (size_t)iy * WW * CC + c;
        #pragma unroll
        for (int j = 0; j < 14; ++j) {
            int ix = w0 - 3 + j;
            in[j] = (ix >= 0 && ix < WW) ? qrow[(size_t)ix * CC] : 0.f;
        }

        #pragma unroll
        for (int i = 0; i < 8; ++i)
            #pragma unroll
            for (int kx = 0; kx < 7; ++kx)
                acc[i] += in[i + kx] * wt[kx];
    }

    // LayerNorm across channels for each of the 8 w-positions.
    // Per-wave shuffle reduce, then combine 4 wave partials via LDS.
    __shared__ float lsum[8][4];
    __shared__ float lsq[8][4];
    int lane = threadIdx.x & 63;
    int wv   = threadIdx.x >> 6;

    #pragma unroll
    for (int i = 0; i < 8; ++i) {
        float v  = acc[i];
        float v2 = v * v;
        #pragma unroll
        for (int m = 1; m < 64; m <<= 1) {
            v  += __shfl_xor(v,  m);
            v2 += __shfl_xor(v2, m);
        }
        if (lane == 0) { lsum[i][wv] = v; lsq[i][wv] = v2; }
    }
    __syncthreads();

    float lw = lnw[c];
    float lb = lnb[c];
    float* qo = qact + (((size_t)n * LQ) + (size_t)h * WW + w0) * CC + c;

    #pragma unroll
    for (int i = 0; i < 8; ++i) {
        float s  = lsum[i][0] + lsum[i][1] + lsum[i][2] + lsum[i][3];
        float s2 = lsq[i][0]  + lsq[i][1]  + lsq[i][2]  + lsq[i][3];
        float mu  = s * (1.0f / 256.0f);
        float var = s2 * (1.0f / 256.0f) - mu * mu;
        float inv = rsqrtf(var + 1e-5f);
        float yv  = (acc[i] - mu) * inv * lw + lb;
        float g = 0.5f * yv * (1.0f + erff(yv * 0.7071067811865475f));
        qo[(size_t)i * CC] = g;
    }
}

// -------------------------------------------------------------------------
// Kernel 2: tiled fp32 GEMM  C = A(MxK) * B(KxN) + bias
// BM=64, BN=64, BK=16, 256 threads, 4x4 microtile.
// MODE 0: plain row-major store (stride Nn)
// MODE 1: store into padded value layout (N, HP, WP, C) at (h+1, w+1)
// -------------------------------------------------------------------------
#define BM 64
#define BN 64
#define BK 16

template <int MODE>
__global__ __launch_bounds__(256) void gemm_tiled(
    const float* __restrict__ A,
    const float* __restrict__ B,
    const float* __restrict__ bias,
    float* __restrict__ Cout,
    int M, int Nn, int K)
{
    __shared__ float As[BK][BM];
    __shared__ float Bs[BK][BN];

    int tid = threadIdx.x;
    int bm  = blockIdx.x * BM;
    int bn  = blockIdx.y * BN;
    int ty  = tid >> 4;   // 0..15
    int tx  = tid & 15;   // 0..15

    int arow = tid >> 2;
    int ak   = (tid & 3) * 4;
    int brow = tid >> 4;
    int bcol = (tid & 15) * 4;

    float acc[4][4] = {};

    for (int k0 = 0; k0 < K; k0 += BK) {
        float4 av = *reinterpret_cast<const float4*>(
            &A[(size_t)(bm + arow) * K + k0 + ak]);
        As[ak + 0][arow] = av.x;
        As[ak + 1][arow] = av.y;
        As[ak + 2][arow] = av.z;
        As[ak + 3][arow] = av.w;

        float4 bv;
        if (bn + bcol < Nn)
            bv = *reinterpret_cast<const float4*>(
                &B[(size_t)(k0 + brow) * Nn + bn + bcol]);
        else
            bv = make_float4(0.f, 0.f, 0.f, 0.f);
        *reinterpret_cast<float4*>(&Bs[brow][bcol]) = bv;

        __syncthreads();
        #pragma unroll
        for (int k = 0; k < BK; ++k) {
            float4 a4 = *reinterpret_cast<const float4*>(&As[k][ty * 4]);
            float4 b4 = *reinterpret_cast<const float4*>(&Bs[k][tx * 4]);
            float aa[4] = {a4.x, a4.y, a4.z, a4.w};
            float bb[4] = {b4.x, b4.y, b4.z, b4.w};
            #pragma unroll
            for (int i = 0; i < 4; ++i)
                #pragma unroll
                for (int j = 0; j < 4; ++j)
                    acc[i][j] += aa[i] * bb[j];
        }
        __syncthreads();
    }

    int row0 = bm + ty * 4;
    int col0 = bn + tx * 4;
    if (col0 >= Nn) return;
    float4 bias4 = *reinterpret_cast<const float4*>(&bias[col0]);

    #pragma unroll
    for (int i = 0; i < 4; ++i) {
        int row = row0 + i;
        float4 o;
        o.x = acc[i][0] + bias4.x;
        o.y = acc[i][1] + bias4.y;
        o.z = acc[i][2] + bias4.z;
        o.w = acc[i][3] + bias4.w;
        if (MODE == 0) {
            *reinterpret_cast<float4*>(&Cout[(size_t)row * Nn + col0]) = o;
        } else {
            int n  = row >> 14;
            int hw = row & 16383;
            int h  = hw >> 7;
            int w  = hw & 127;
            size_t dst = (((size_t)n * HPP + (h + 1)) * WPP + (w + 1)) * CC + col0;
            *reinterpret_cast<float4*>(&Cout[dst]) = o;
        }
    }
}

// -------------------------------------------------------------------------
// Kernel 3: deformable bilinear sampling + attention-weighted sum
// One block per (n,l); 256 threads = output channels (head = c/32).
// -------------------------------------------------------------------------
__global__ __launch_bounds__(256) void sampler_kernel(
    const float* __restrict__ rp,     // (N, LQ, 1, 2)
    const float* __restrict__ offb,   // (N*LQ, 64) raw offsets
    const float* __restrict__ attnb,  // (N*LQ, 32) raw logits
    const float* __restrict__ vpad,   // (N, HP, WP, C)
    float* __restrict__ outb)         // (N*LQ, C)
{
    int row  = blockIdx.x;            // n*LQ + l
    int c    = threadIdx.x;
    int n    = row >> 14;
    int head = c >> 5;

    float ref0 = rp[(size_t)row * 2 + 0];
    float ref1 = rp[(size_t)row * 2 + 1];

    const float GY[4] = {0.f, 0.f, 1.f, 1.f};
    const float GX[4] = {0.f, 1.f, 0.f, 1.f};

    const float* vbase = vpad + (size_t)n * HPP * WPP * CC;
    float acc = 0.f;

    #pragma unroll
    for (int p = 0; p < 4; ++p) {
        float o0 = offb[(size_t)row * 64 + head * 8 + p * 2 + 0];
        float o1 = offb[(size_t)row * 64 + head * 8 + p * 2 + 1];
        float al = attnb[(size_t)row * 32 + head * 4 + p];
        float a  = 1.0f / (1.0f + expf(-al));

        float x = ref0 * WPP + GY[p] + o0 - 0.5f;
        float y = ref1 * HPP + GX[p] + o1 - 0.5f;

        float x0f = floorf(x), y0f = floorf(y);
        int   x0  = (int)x0f,  y0  = (int)y0f;
        float wx1 = x - x0f, wx0 = 1.f - wx1;
        float wy1 = y - y0f, wy0 = 1.f - wy1;

        float s = 0.f;
        {
            int xi = x0, yi = y0;
            if (xi >= 0 && xi < WPP && yi >= 0 && yi < HPP)
                s += wx0 * wy0 * vbase[((size_t)yi * WPP + xi) * CC + c];
        }
        {
            int xi = x0 + 1, yi = y0;
            if (xi >= 0 && xi < WPP && yi >= 0 && yi < HPP)
                s += wx1 * wy0 * vbase[((size_t)yi * WPP + xi) * CC + c];
        }
        {
            int xi = x0, yi = y0 + 1;
            if (xi >= 0 && xi < WPP && yi >= 0 && yi < HPP)
                s += wx0 * wy1 * vbase[((size_t)yi * WPP + xi) * CC + c];
        }
        {
            int xi = x0 + 1, yi = y0 + 1;
            if (xi >= 0 && xi < WPP && yi >= 0 && yi < HPP)
                s += wx1 * wy1 * vbase[((size_t)yi * WPP + xi) * CC + c];
        }
        acc += a * s;
    }
    outb[(size_t)row * CC + c] = acc;
}

// -------------------------------------------------------------------------
extern "C" void kernel_launch(void* const* d_in, const int* in_sizes, int n_in,
                              void* d_out, int out_size, void* d_ws, size_t ws_size,
                              hipStream_t stream)
{
    const float* query = (const float*)d_in[0];
    const float* rp    = (const float*)d_in[1];
    const float* dwk   = (const float*)d_in[4];
    const float* dwb   = (const float*)d_in[5];
    const float* lnw   = (const float*)d_in[6];
    const float* lnb   = (const float*)d_in[7];
    const float* Woff  = (const float*)d_in[8];
    const float* boff  = (const float*)d_in[9];
    const float* Wattn = (const float*)d_in[10];
    const float* battn = (const float*)d_in[11];
    const float* Wval  = (const float*)d_in[12];
    const float* bval  = (const float*)d_in[13];
    const float* Wout  = (const float*)d_in[14];
    const float* bout  = (const float*)d_in[15];
    float* out = (float*)d_out;

    const int M = NB * LQ;  // 32768

    // workspace layout (floats)
    float* q_act    = (float*)d_ws;                        //  8,388,608
    float* v_pad    = q_act + (size_t)M * CC;              //  8,652,800
    float* offb     = v_pad + (size_t)NB * HPP * WPP * CC; //  2,097,152
    float* attnb    = offb + (size_t)M * 64;               //  1,048,576
    float* kt       = attnb + (size_t)M * 32;              //  12,544
    float* out_attn = q_act;  // alias: q_act dead after attn GEMM

    // zero padded value buffer (borders must be 0)
    hipMemsetAsync(v_pad, 0, (size_t)NB * HPP * WPP * CC * sizeof(float), stream);

    // 0) transpose depthwise weights for coalesced access
    transpose_w_kernel<<<49, 256, 0, stream>>>(dwk, kt);

    // 1) conv + LN + GELU (8 outputs per thread along w)
    {
        dim3 grid(WW / 8, HH, NB);
        conv_ln_gelu_kernel<<<grid, 256, 0, stream>>>(
            query, kt, dwb, lnw, lnb, q_act);
    }

    // 2) value GEMM -> padded layout
    {
        dim3 grid(M / BM, CC / BN);
        gemm_tiled<1><<<grid, 256, 0, stream>>>(q_act, Wval, bval, v_pad, M, CC, CC);
    }
    // 3) offsets GEMM (N=64)
    {
        dim3 grid(M / BM, 1);
        gemm_tiled<0><<<grid, 256, 0, stream>>>(q_act, Woff, boff, offb, M, 64, CC);
    }
    // 4) attn logits GEMM (N=32)
    {
        dim3 grid(M / BM, 1);
        gemm_tiled<0><<<grid, 256, 0, stream>>>(q_act, Wattn, battn, attnb, M, 32, CC);
    }
    // 5) sampling + weighted sum
    sampler_kernel<<<M, 256, 0, stream>>>(rp, offb, attnb, v_pad, out_attn);

    // 6) output GEMM
    {
        dim3 grid(M / BM, CC / BN);
        gemm_tiled<0><<<grid, 256, 0, stream>>>(out_attn, Wout, bout, out, M, CC, CC);
    }
}

// Round 3
// 260.665 us; speedup vs baseline: 4.6716x; 1.2678x over previous
//
#include <hip/hip_runtime.h>
#include <math.h>

// Problem constants
#define NB   2
#define CC   256
#define HH   128
#define WW   128
#define NHD  8
#define PP   4
#define DHD  32
#define HPP  130
#define WPP  130
#define LQ   16384   // HH*WW

// -------------------------------------------------------------------------
// Kernel 0: transpose depthwise weights (C,49) -> (49,C) for coalesced loads
// -------------------------------------------------------------------------
__global__ __launch_bounds__(256) void transpose_w_kernel(
    const float* __restrict__ kern,   // (C, 49)
    float* __restrict__ kt)           // (49, C)
{
    int c = threadIdx.x;              // 0..255
    int k = blockIdx.x;               // 0..48
    kt[k * CC + c] = kern[c * 49 + k];
}

// -------------------------------------------------------------------------
// Kernel 1: fused depthwise 7x7 conv + bias + channel-LayerNorm + exact GELU
// Block = one (n, h) row segment of 8 w-positions; 256 threads = channels.
// -------------------------------------------------------------------------
__global__ __launch_bounds__(256) void conv_ln_gelu_kernel(
    const float* __restrict__ q,      // (N, LQ, C)
    const float* __restrict__ kt,     // (49, C) transposed weights
    const float* __restrict__ kbias,  // (C)
    const float* __restrict__ lnw,    // (C)
    const float* __restrict__ lnb,    // (C)
    float* __restrict__ qact)         // (N, LQ, C)
{
    int c  = threadIdx.x;
    int w0 = blockIdx.x * 8;          // 16 tiles across W=128
    int h  = blockIdx.y;
    int n  = blockIdx.z;

    const float* qn = q + (size_t)n * LQ * CC;

    float bias = kbias[c];
    float acc[8];
    #pragma unroll
    for (int i = 0; i < 8; ++i) acc[i] = bias;

    #pragma unroll
    for (int ky = 0; ky < 7; ++ky) {
        int iy = h + ky - 3;
        if (iy < 0 || iy >= HH) continue;

        float wt[7];
        #pragma unroll
        for (int kx = 0; kx < 7; ++kx)
            wt[kx] = kt[(ky * 7 + kx) * CC + c];

        float in[14];
        const float* qrow = qn + (size_t)iy * WW * CC + c;
        #pragma unroll
        for (int j = 0; j < 14; ++j) {
            int ix = w0 - 3 + j;
            in[j] = (ix >= 0 && ix < WW) ? qrow[(size_t)ix * CC] : 0.f;
        }

        #pragma unroll
        for (int i = 0; i < 8; ++i)
            #pragma unroll
            for (int kx = 0; kx < 7; ++kx)
                acc[i] += in[i + kx] * wt[kx];
    }

    __shared__ float lsum[8][4];
    __shared__ float lsq[8][4];
    int lane = threadIdx.x & 63;
    int wv   = threadIdx.x >> 6;

    #pragma unroll
    for (int i = 0; i < 8; ++i) {
        float v  = acc[i];
        float v2 = v * v;
        #pragma unroll
        for (int m = 1; m < 64; m <<= 1) {
            v  += __shfl_xor(v,  m);
            v2 += __shfl_xor(v2, m);
        }
        if (lane == 0) { lsum[i][wv] = v; lsq[i][wv] = v2; }
    }
    __syncthreads();

    float lw = lnw[c];
    float lb = lnb[c];
    float* qo = qact + (((size_t)n * LQ) + (size_t)h * WW + w0) * CC + c;

    #pragma unroll
    for (int i = 0; i < 8; ++i) {
        float s  = lsum[i][0] + lsum[i][1] + lsum[i][2] + lsum[i][3];
        float s2 = lsq[i][0]  + lsq[i][1]  + lsq[i][2]  + lsq[i][3];
        float mu  = s * (1.0f / 256.0f);
        float var = s2 * (1.0f / 256.0f) - mu * mu;
        float inv = rsqrtf(var + 1e-5f);
        float yv  = (acc[i] - mu) * inv * lw + lb;
        float g = 0.5f * yv * (1.0f + erff(yv * 0.7071067811865475f));
        qo[(size_t)i * CC] = g;
    }
}

// -------------------------------------------------------------------------
// Kernel 2: tiled fp32 GEMM  C = A(MxK) * B(KxN) + bias
// -------------------------------------------------------------------------
#define BM 64
#define BN 64
#define BK 16

template <int MODE>
__global__ __launch_bounds__(256) void gemm_tiled(
    const float* __restrict__ A,
    const float* __restrict__ B,
    const float* __restrict__ bias,
    float* __restrict__ Cout,
    int M, int Nn, int K)
{
    __shared__ float As[BK][BM];
    __shared__ float Bs[BK][BN];

    int tid = threadIdx.x;
    int bm  = blockIdx.x * BM;
    int bn  = blockIdx.y * BN;
    int ty  = tid >> 4;
    int tx  = tid & 15;

    int arow = tid >> 2;
    int ak   = (tid & 3) * 4;
    int brow = tid >> 4;
    int bcol = (tid & 15) * 4;

    float acc[4][4] = {};

    for (int k0 = 0; k0 < K; k0 += BK) {
        float4 av = *reinterpret_cast<const float4*>(
            &A[(size_t)(bm + arow) * K + k0 + ak]);
        As[ak + 0][arow] = av.x;
        As[ak + 1][arow] = av.y;
        As[ak + 2][arow] = av.z;
        As[ak + 3][arow] = av.w;

        float4 bv;
        if (bn + bcol < Nn)
            bv = *reinterpret_cast<const float4*>(
                &B[(size_t)(k0 + brow) * Nn + bn + bcol]);
        else
            bv = make_float4(0.f, 0.f, 0.f, 0.f);
        *reinterpret_cast<float4*>(&Bs[brow][bcol]) = bv;

        __syncthreads();
        #pragma unroll
        for (int k = 0; k < BK; ++k) {
            float4 a4 = *reinterpret_cast<const float4*>(&As[k][ty * 4]);
            float4 b4 = *reinterpret_cast<const float4*>(&Bs[k][tx * 4]);
            float aa[4] = {a4.x, a4.y, a4.z, a4.w};
            float bb[4] = {b4.x, b4.y, b4.z, b4.w};
            #pragma unroll
            for (int i = 0; i < 4; ++i)
                #pragma unroll
                for (int j = 0; j < 4; ++j)
                    acc[i][j] += aa[i] * bb[j];
        }
        __syncthreads();
    }

    int row0 = bm + ty * 4;
    int col0 = bn + tx * 4;
    if (col0 >= Nn) return;
    float4 bias4 = *reinterpret_cast<const float4*>(&bias[col0]);

    #pragma unroll
    for (int i = 0; i < 4; ++i) {
        int row = row0 + i;
        float4 o;
        o.x = acc[i][0] + bias4.x;
        o.y = acc[i][1] + bias4.y;
        o.z = acc[i][2] + bias4.z;
        o.w = acc[i][3] + bias4.w;
        if (MODE == 0) {
            *reinterpret_cast<float4*>(&Cout[(size_t)row * Nn + col0]) = o;
        } else {
            int n  = row >> 14;
            int hw = row & 16383;
            int h  = hw >> 7;
            int w  = hw & 127;
            size_t dst = (((size_t)n * HPP + (h + 1)) * WPP + (w + 1)) * CC + col0;
            *reinterpret_cast<float4*>(&Cout[dst]) = o;
        }
    }
}

// -------------------------------------------------------------------------
// Kernel 3: deformable bilinear sampling + attention-weighted sum
// Two-phase: phase 1 computes per-(row,head,p) corner indices + fused
// weights once (128 threads), stores to LDS; phase 2: thread = 4 channels
// (float4 gathers), 4 rows per block.
// -------------------------------------------------------------------------
__global__ __launch_bounds__(256) void sampler_kernel(
    const float* __restrict__ rp,     // (N, LQ, 1, 2)
    const float* __restrict__ offb,   // (N*LQ, 64) raw offsets
    const float* __restrict__ attnb,  // (N*LQ, 32) raw logits
    const float* __restrict__ vpad,   // (N, HP, WP, C)
    float* __restrict__ outb)         // (N*LQ, C)
{
    // [row_local][p][head] layout -> phase-2 reads (fixed p, head 0..7
    // consecutive) are 8 consecutive 16B slots = conflict-free b128.
    __shared__ int4   sIdx[4][4][8];
    __shared__ float4 sW[4][4][8];

    int tid  = threadIdx.x;
    int row0 = blockIdx.x * 4;

    // ---- Phase 1: 128 threads, one (row_local, head, p) each ----
    if (tid < 128) {
        int rl   = tid >> 5;          // 0..3
        int hp   = tid & 31;
        int head = hp >> 2;
        int p    = hp & 3;
        int row  = row0 + rl;

        float ref0 = rp[(size_t)row * 2 + 0];
        float ref1 = rp[(size_t)row * 2 + 1];
        float o0 = offb[(size_t)row * 64 + head * 8 + p * 2 + 0];
        float o1 = offb[(size_t)row * 64 + head * 8 + p * 2 + 1];
        float al = attnb[(size_t)row * 32 + head * 4 + p];
        float a  = 1.0f / (1.0f + expf(-al));

        // grid: x uses ky = {0,0,1,1}, y uses kx = {0,1,0,1}
        float gy = (float)(p >> 1);
        float gx = (float)(p & 1);
        float x = ref0 * WPP + gy + o0 - 0.5f;
        float y = ref1 * HPP + gx + o1 - 0.5f;

        float x0f = floorf(x), y0f = floorf(y);
        int   x0  = (int)x0f,  y0  = (int)y0f;
        float wx1 = x - x0f, wx0 = 1.f - wx1;
        float wy1 = y - y0f, wy0 = 1.f - wy1;
        int x1 = x0 + 1, y1 = y0 + 1;

        bool vx0 = (x0 >= 0) & (x0 < WPP);
        bool vx1 = (x1 >= 0) & (x1 < WPP);
        bool vy0 = (y0 >= 0) & (y0 < HPP);
        bool vy1 = (y1 >= 0) & (y1 < HPP);
        int cx0 = min(max(x0, 0), WPP - 1);
        int cx1 = min(max(x1, 0), WPP - 1);
        int cy0 = min(max(y0, 0), HPP - 1);
        int cy1 = min(max(y1, 0), HPP - 1);

        int4 id;
        id.x = cy0 * WPP + cx0;
        id.y = cy0 * WPP + cx1;
        id.z = cy1 * WPP + cx0;
        id.w = cy1 * WPP + cx1;
        float4 w;
        w.x = (vx0 && vy0) ? a * wx0 * wy0 : 0.f;
        w.y = (vx1 && vy0) ? a * wx1 * wy0 : 0.f;
        w.z = (vx0 && vy1) ? a * wx0 * wy1 : 0.f;
        w.w = (vx1 && vy1) ? a * wx1 * wy1 : 0.f;

        sIdx[rl][p][head] = id;
        sW[rl][p][head]   = w;
    }
    __syncthreads();

    // ---- Phase 2: thread = 4 channels; wave = one row ----
    int rl   = tid >> 6;              // 0..3
    int c0   = (tid & 63) * 4;        // channel base
    int head = c0 >> 5;
    int row  = row0 + rl;
    int n    = row >> 14;
    const float* vbase = vpad + (size_t)n * HPP * WPP * CC + c0;

    float4 acc = make_float4(0.f, 0.f, 0.f, 0.f);
    #pragma unroll
    for (int p = 0; p < 4; ++p) {
        int4   id = sIdx[rl][p][head];
        float4 w  = sW[rl][p][head];
        float4 g0 = *reinterpret_cast<const float4*>(vbase + (size_t)id.x * CC);
        float4 g1 = *reinterpret_cast<const float4*>(vbase + (size_t)id.y * CC);
        float4 g2 = *reinterpret_cast<const float4*>(vbase + (size_t)id.z * CC);
        float4 g3 = *reinterpret_cast<const float4*>(vbase + (size_t)id.w * CC);
        acc.x += w.x * g0.x + w.y * g1.x + w.z * g2.x + w.w * g3.x;
        acc.y += w.x * g0.y + w.y * g1.y + w.z * g2.y + w.w * g3.y;
        acc.z += w.x * g0.z + w.y * g1.z + w.z * g2.z + w.w * g3.z;
        acc.w += w.x * g0.w + w.y * g1.w + w.z * g2.w + w.w * g3.w;
    }
    *reinterpret_cast<float4*>(&outb[(size_t)row * CC + c0]) = acc;
}

// -------------------------------------------------------------------------
extern "C" void kernel_launch(void* const* d_in, const int* in_sizes, int n_in,
                              void* d_out, int out_size, void* d_ws, size_t ws_size,
                              hipStream_t stream)
{
    const float* query = (const float*)d_in[0];
    const float* rp    = (const float*)d_in[1];
    const float* dwk   = (const float*)d_in[4];
    const float* dwb   = (const float*)d_in[5];
    const float* lnw   = (const float*)d_in[6];
    const float* lnb   = (const float*)d_in[7];
    const float* Woff  = (const float*)d_in[8];
    const float* boff  = (const float*)d_in[9];
    const float* Wattn = (const float*)d_in[10];
    const float* battn = (const float*)d_in[11];
    const float* Wval  = (const float*)d_in[12];
    const float* bval  = (const float*)d_in[13];
    const float* Wout  = (const float*)d_in[14];
    const float* bout  = (const float*)d_in[15];
    float* out = (float*)d_out;

    const int M = NB * LQ;  // 32768

    // workspace layout (floats)
    float* q_act    = (float*)d_ws;                        //  8,388,608
    float* v_pad    = q_act + (size_t)M * CC;              //  8,652,800
    float* offb     = v_pad + (size_t)NB * HPP * WPP * CC; //  2,097,152
    float* attnb    = offb + (size_t)M * 64;               //  1,048,576
    float* kt       = attnb + (size_t)M * 32;              //  12,544
    float* out_attn = q_act;  // alias: q_act dead after attn GEMM

    hipMemsetAsync(v_pad, 0, (size_t)NB * HPP * WPP * CC * sizeof(float), stream);

    transpose_w_kernel<<<49, 256, 0, stream>>>(dwk, kt);

    {
        dim3 grid(WW / 8, HH, NB);
        conv_ln_gelu_kernel<<<grid, 256, 0, stream>>>(
            query, kt, dwb, lnw, lnb, q_act);
    }

    {
        dim3 grid(M / BM, CC / BN);
        gemm_tiled<1><<<grid, 256, 0, stream>>>(q_act, Wval, bval, v_pad, M, CC, CC);
    }
    {
        dim3 grid(M / BM, 1);
        gemm_tiled<0><<<grid, 256, 0, stream>>>(q_act, Woff, boff, offb, M, 64, CC);
    }
    {
        dim3 grid(M / BM, 1);
        gemm_tiled<0><<<grid, 256, 0, stream>>>(q_act, Wattn, battn, attnb, M, 32, CC);
    }

    sampler_kernel<<<M / 4, 256, 0, stream>>>(rp, offb, attnb, v_pad, out_attn);

    {
        dim3 grid(M / BM, CC / BN);
        gemm_tiled<0><<<grid, 256, 0, stream>>>(out_attn, Wout, bout, out, M, CC, CC);
    }
}

// Round 4
// 136.616 us; speedup vs baseline: 8.9135x; 1.9080x over previous
//
#include <hip/hip_runtime.h>
#include <hip/hip_bf16.h>
#include <math.h>

// Problem constants
#define NB   2
#define CC   256
#define HH   128
#define WW   128
#define HPP  130
#define WPP  130
#define LQ   16384   // HH*WW

typedef __attribute__((ext_vector_type(8))) short short8;
typedef __attribute__((ext_vector_type(4))) float f32x4;
typedef __attribute__((ext_vector_type(4))) unsigned int u32x4;

static __device__ __forceinline__ unsigned short f2bf(float f) {
    __hip_bfloat16 h = __float2bfloat16(f);
    return __builtin_bit_cast(unsigned short, h);
}

// -------------------------------------------------------------------------
// Kernel 0a: transpose depthwise weights (C,49) -> (49,C), fp32
// -------------------------------------------------------------------------
__global__ __launch_bounds__(256) void transpose_w_kernel(
    const float* __restrict__ kern, float* __restrict__ kt)
{
    int c = threadIdx.x;
    int k = blockIdx.x;
    kt[k * CC + c] = kern[c * 49 + k];
}

// -------------------------------------------------------------------------
// Kernel 0b: convert+transpose GEMM weights (256,N) f32 -> (N,256) bf16
// -------------------------------------------------------------------------
__global__ __launch_bounds__(256) void convert_transpose_kernel(
    const float* __restrict__ W, unsigned short* __restrict__ Wt, int N)
{
    int k = blockIdx.x;       // 0..255
    int n = threadIdx.x;      // 0..N-1 (N==256)
    Wt[(size_t)n * 256 + k] = f2bf(W[(size_t)k * N + n]);
}

// -------------------------------------------------------------------------
// Kernel 0c: fuse W_off (256,64) + W_attn (256,32) -> (128,256) bf16 Wt
// rows 96..127 zero; bias_oa[128] likewise.
// -------------------------------------------------------------------------
__global__ __launch_bounds__(128) void prep_oa_kernel(
    const float* __restrict__ Woff, const float* __restrict__ boff,
    const float* __restrict__ Wattn, const float* __restrict__ battn,
    unsigned short* __restrict__ Wt, float* __restrict__ bias)
{
    int k = blockIdx.x;   // 0..255
    int n = threadIdx.x;  // 0..127
    float v = 0.f, bb = 0.f;
    if (n < 64)      { v = Woff[(size_t)k * 64 + n];        bb = boff[n]; }
    else if (n < 96) { v = Wattn[(size_t)k * 32 + (n - 64)]; bb = battn[n - 64]; }
    Wt[(size_t)n * 256 + k] = f2bf(v);
    if (k == 0) bias[n] = bb;
}

// -------------------------------------------------------------------------
// Kernel 1: fused depthwise 7x7 conv + bias + channel-LN + exact GELU
// writes q_act as bf16
// -------------------------------------------------------------------------
__global__ __launch_bounds__(256) void conv_ln_gelu_kernel(
    const float* __restrict__ q,      // (N, LQ, C)
    const float* __restrict__ kt,     // (49, C)
    const float* __restrict__ kbias,
    const float* __restrict__ lnw,
    const float* __restrict__ lnb,
    unsigned short* __restrict__ qact) // (N, LQ, C) bf16
{
    int c  = threadIdx.x;
    int w0 = blockIdx.x * 8;
    int h  = blockIdx.y;
    int n  = blockIdx.z;

    const float* qn = q + (size_t)n * LQ * CC;

    float bias = kbias[c];
    float acc[8];
    #pragma unroll
    for (int i = 0; i < 8; ++i) acc[i] = bias;

    #pragma unroll
    for (int ky = 0; ky < 7; ++ky) {
        int iy = h + ky - 3;
        if (iy < 0 || iy >= HH) continue;

        float wt[7];
        #pragma unroll
        for (int kx = 0; kx < 7; ++kx)
            wt[kx] = kt[(ky * 7 + kx) * CC + c];

        float in[14];
        const float* qrow = qn + (size_t)iy * WW * CC + c;
        #pragma unroll
        for (int j = 0; j < 14; ++j) {
            int ix = w0 - 3 + j;
            in[j] = (ix >= 0 && ix < WW) ? qrow[(size_t)ix * CC] : 0.f;
        }

        #pragma unroll
        for (int i = 0; i < 8; ++i)
            #pragma unroll
            for (int kx = 0; kx < 7; ++kx)
                acc[i] += in[i + kx] * wt[kx];
    }

    __shared__ float lsum[8][4];
    __shared__ float lsq[8][4];
    int lane = threadIdx.x & 63;
    int wv   = threadIdx.x >> 6;

    #pragma unroll
    for (int i = 0; i < 8; ++i) {
        float v  = acc[i];
        float v2 = v * v;
        #pragma unroll
        for (int m = 1; m < 64; m <<= 1) {
            v  += __shfl_xor(v,  m);
            v2 += __shfl_xor(v2, m);
        }
        if (lane == 0) { lsum[i][wv] = v; lsq[i][wv] = v2; }
    }
    __syncthreads();

    float lw = lnw[c];
    float lb = lnb[c];
    unsigned short* qo = qact + (((size_t)n * LQ) + (size_t)h * WW + w0) * CC + c;

    #pragma unroll
    for (int i = 0; i < 8; ++i) {
        float s  = lsum[i][0] + lsum[i][1] + lsum[i][2] + lsum[i][3];
        float s2 = lsq[i][0]  + lsq[i][1]  + lsq[i][2]  + lsq[i][3];
        float mu  = s * (1.0f / 256.0f);
        float var = s2 * (1.0f / 256.0f) - mu * mu;
        float inv = rsqrtf(var + 1e-5f);
        float yv  = (acc[i] - mu) * inv * lw + lb;
        float g = 0.5f * yv * (1.0f + erff(yv * 0.7071067811865475f));
        qo[(size_t)i * CC] = f2bf(g);
    }
}

// -------------------------------------------------------------------------
// Kernel 2: bf16 MFMA GEMM  C(f32) = A(M,256)bf16 * Bt(Nn,256)bf16^T + bias
// 128x128 tile, BK=64, 4 waves (2x2), 4x4 16x16x32 frags per wave.
// MODE 0: row-major store; MODE 1: padded value layout (N,HP,WP,C)
// -------------------------------------------------------------------------
template <int MODE>
__global__ __launch_bounds__(256) void gemm_mfma(
    const unsigned short* __restrict__ A,
    const unsigned short* __restrict__ Bt,
    const float* __restrict__ bias,
    float* __restrict__ C,
    int Nn)
{
    __shared__ unsigned short Al[128][72];
    __shared__ unsigned short Bl[128][72];

    int t    = threadIdx.x;
    int bm   = blockIdx.x * 128;
    int bn   = blockIdx.y * 128;
    int wid  = t >> 6;
    int lane = t & 63;
    int wr   = wid >> 1;
    int wc   = wid & 1;
    int lr   = lane & 15;
    int lg   = lane >> 4;

    int srow = t >> 1;
    int sseg = (t & 1) << 5;   // 0 or 32 bf16

    const unsigned short* gA = A + (size_t)(bm + srow) * 256 + sseg;
    const unsigned short* gB = Bt + (size_t)(bn + srow) * 256 + sseg;
    unsigned short* lA = &Al[srow][sseg];
    unsigned short* lB = &Bl[srow][sseg];

    f32x4 acc[4][4] = {};

    for (int kt = 0; kt < 4; ++kt) {
        const unsigned short* ga = gA + kt * 64;
        const unsigned short* gb = gB + kt * 64;
        u32x4 a0 = *(const u32x4*)(ga);
        u32x4 a1 = *(const u32x4*)(ga + 8);
        u32x4 a2 = *(const u32x4*)(ga + 16);
        u32x4 a3 = *(const u32x4*)(ga + 24);
        u32x4 b0 = *(const u32x4*)(gb);
        u32x4 b1 = *(const u32x4*)(gb + 8);
        u32x4 b2 = *(const u32x4*)(gb + 16);
        u32x4 b3 = *(const u32x4*)(gb + 24);
        *(u32x4*)(lA)      = a0;
        *(u32x4*)(lA + 8)  = a1;
        *(u32x4*)(lA + 16) = a2;
        *(u32x4*)(lA + 24) = a3;
        *(u32x4*)(lB)      = b0;
        *(u32x4*)(lB + 8)  = b1;
        *(u32x4*)(lB + 16) = b2;
        *(u32x4*)(lB + 24) = b3;
        __syncthreads();

        #pragma unroll
        for (int kk = 0; kk < 2; ++kk) {
            short8 af[4], bfr[4];
            #pragma unroll
            for (int m = 0; m < 4; ++m)
                af[m] = *(const short8*)(&Al[wr * 64 + m * 16 + lr][kk * 32 + lg * 8]);
            #pragma unroll
            for (int n = 0; n < 4; ++n)
                bfr[n] = *(const short8*)(&Bl[wc * 64 + n * 16 + lr][kk * 32 + lg * 8]);
            #pragma unroll
            for (int m = 0; m < 4; ++m)
                #pragma unroll
                for (int n = 0; n < 4; ++n)
                    acc[m][n] = __builtin_amdgcn_mfma_f32_16x16x32_bf16(
                        af[m], bfr[n], acc[m][n], 0, 0, 0);
        }
        __syncthreads();
    }

    float bv[4];
    #pragma unroll
    for (int n = 0; n < 4; ++n) bv[n] = bias[bn + wc * 64 + n * 16 + lr];

    #pragma unroll
    for (int m = 0; m < 4; ++m) {
        #pragma unroll
        for (int j = 0; j < 4; ++j) {
            int row = bm + wr * 64 + m * 16 + lg * 4 + j;
            size_t rbase;
            if (MODE == 0) {
                rbase = (size_t)row * Nn;
            } else {
                int nb = row >> 14;
                int hw = row & 16383;
                int h  = hw >> 7;
                int w  = hw & 127;
                rbase = (((size_t)nb * HPP + (h + 1)) * WPP + (w + 1)) * CC;
            }
            #pragma unroll
            for (int n = 0; n < 4; ++n) {
                int col = bn + wc * 64 + n * 16 + lr;
                C[rbase + col] = acc[m][n][j] + bv[n];
            }
        }
    }
}

// -------------------------------------------------------------------------
// Kernel 3: deformable bilinear sampling + attention-weighted sum
// reads fused oa buffer (M,128) f32; writes out_attn bf16
// -------------------------------------------------------------------------
__global__ __launch_bounds__(256) void sampler_kernel(
    const float* __restrict__ rp,     // (N, LQ, 1, 2)
    const float* __restrict__ oa,     // (N*LQ, 128): [0:64]=off, [64:96]=logits
    const float* __restrict__ vpad,   // (N, HP, WP, C)
    unsigned short* __restrict__ outb) // (N*LQ, C) bf16
{
    __shared__ int4   sIdx[4][4][8];
    __shared__ float4 sW[4][4][8];

    int tid  = threadIdx.x;
    int row0 = blockIdx.x * 4;

    if (tid < 128) {
        int rl   = tid >> 5;
        int hp   = tid & 31;
        int head = hp >> 2;
        int p    = hp & 3;
        int row  = row0 + rl;

        float ref0 = rp[(size_t)row * 2 + 0];
        float ref1 = rp[(size_t)row * 2 + 1];
        float o0 = oa[(size_t)row * 128 + head * 8 + p * 2 + 0];
        float o1 = oa[(size_t)row * 128 + head * 8 + p * 2 + 1];
        float al = oa[(size_t)row * 128 + 64 + head * 4 + p];
        float a  = 1.0f / (1.0f + expf(-al));

        float gy = (float)(p >> 1);
        float gx = (float)(p & 1);
        float x = ref0 * WPP + gy + o0 - 0.5f;
        float y = ref1 * HPP + gx + o1 - 0.5f;

        float x0f = floorf(x), y0f = floorf(y);
        int   x0  = (int)x0f,  y0  = (int)y0f;
        float wx1 = x - x0f, wx0 = 1.f - wx1;
        float wy1 = y - y0f, wy0 = 1.f - wy1;
        int x1 = x0 + 1, y1 = y0 + 1;

        bool vx0 = (x0 >= 0) & (x0 < WPP);
        bool vx1 = (x1 >= 0) & (x1 < WPP);
        bool vy0 = (y0 >= 0) & (y0 < HPP);
        bool vy1 = (y1 >= 0) & (y1 < HPP);
        int cx0 = min(max(x0, 0), WPP - 1);
        int cx1 = min(max(x1, 0), WPP - 1);
        int cy0 = min(max(y0, 0), HPP - 1);
        int cy1 = min(max(y1, 0), HPP - 1);

        int4 id;
        id.x = cy0 * WPP + cx0;
        id.y = cy0 * WPP + cx1;
        id.z = cy1 * WPP + cx0;
        id.w = cy1 * WPP + cx1;
        float4 w;
        w.x = (vx0 && vy0) ? a * wx0 * wy0 : 0.f;
        w.y = (vx1 && vy0) ? a * wx1 * wy0 : 0.f;
        w.z = (vx0 && vy1) ? a * wx0 * wy1 : 0.f;
        w.w = (vx1 && vy1) ? a * wx1 * wy1 : 0.f;

        sIdx[rl][p][head] = id;
        sW[rl][p][head]   = w;
    }
    __syncthreads();

    int rl   = tid >> 6;
    int c0   = (tid & 63) * 4;
    int head = c0 >> 5;
    int row  = row0 + rl;
    int n    = row >> 14;
    const float* vbase = vpad + (size_t)n * HPP * WPP * CC + c0;

    float4 acc = make_float4(0.f, 0.f, 0.f, 0.f);
    #pragma unroll
    for (int p = 0; p < 4; ++p) {
        int4   id = sIdx[rl][p][head];
        float4 w  = sW[rl][p][head];
        float4 g0 = *reinterpret_cast<const float4*>(vbase + (size_t)id.x * CC);
        float4 g1 = *reinterpret_cast<const float4*>(vbase + (size_t)id.y * CC);
        float4 g2 = *reinterpret_cast<const float4*>(vbase + (size_t)id.z * CC);
        float4 g3 = *reinterpret_cast<const float4*>(vbase + (size_t)id.w * CC);
        acc.x += w.x * g0.x + w.y * g1.x + w.z * g2.x + w.w * g3.x;
        acc.y += w.x * g0.y + w.y * g1.y + w.z * g2.y + w.w * g3.y;
        acc.z += w.x * g0.z + w.y * g1.z + w.z * g2.z + w.w * g3.z;
        acc.w += w.x * g0.w + w.y * g1.w + w.z * g2.w + w.w * g3.w;
    }
    ushort4 o;
    o.x = f2bf(acc.x);
    o.y = f2bf(acc.y);
    o.z = f2bf(acc.z);
    o.w = f2bf(acc.w);
    *reinterpret_cast<ushort4*>(&outb[(size_t)row * CC + c0]) = o;
}

// -------------------------------------------------------------------------
extern "C" void kernel_launch(void* const* d_in, const int* in_sizes, int n_in,
                              void* d_out, int out_size, void* d_ws, size_t ws_size,
                              hipStream_t stream)
{
    const float* query = (const float*)d_in[0];
    const float* rp    = (const float*)d_in[1];
    const float* dwk   = (const float*)d_in[4];
    const float* dwb   = (const float*)d_in[5];
    const float* lnw   = (const float*)d_in[6];
    const float* lnb   = (const float*)d_in[7];
    const float* Woff  = (const float*)d_in[8];
    const float* boff  = (const float*)d_in[9];
    const float* Wattn = (const float*)d_in[10];
    const float* battn = (const float*)d_in[11];
    const float* Wval  = (const float*)d_in[12];
    const float* bval  = (const float*)d_in[13];
    const float* Wout  = (const float*)d_in[14];
    const float* bout  = (const float*)d_in[15];
    float* out = (float*)d_out;

    const int M = NB * LQ;  // 32768

    // workspace layout (bytes)
    uint8_t* w8 = (uint8_t*)d_ws;
    unsigned short* q_act  = (unsigned short*)w8;                    // 16,777,216
    float*          v_pad  = (float*)(w8 + 16777216);                // 34,611,200
    float*          oa     = (float*)(w8 + 51388416);                // 16,777,216
    unsigned short* wt_val = (unsigned short*)(w8 + 68165632);       //    131,072
    unsigned short* wt_out = (unsigned short*)(w8 + 68296704);       //    131,072
    unsigned short* wt_oa  = (unsigned short*)(w8 + 68427776);       //     65,536
    float*          b_oa   = (float*)(w8 + 68493312);                //        512
    float*          kt     = (float*)(w8 + 68493824);                //     50,176
    unsigned short* out_attn = q_act;  // alias: q_act dead after oa GEMM

    hipMemsetAsync(v_pad, 0, (size_t)NB * HPP * WPP * CC * sizeof(float), stream);

    // prep: weight transforms
    transpose_w_kernel<<<49, 256, 0, stream>>>(dwk, kt);
    convert_transpose_kernel<<<256, 256, 0, stream>>>(Wval, wt_val, 256);
    convert_transpose_kernel<<<256, 256, 0, stream>>>(Wout, wt_out, 256);
    prep_oa_kernel<<<256, 128, 0, stream>>>(Woff, boff, Wattn, battn, wt_oa, b_oa);

    // 1) conv + LN + GELU -> bf16 q_act
    {
        dim3 grid(WW / 8, HH, NB);
        conv_ln_gelu_kernel<<<grid, 256, 0, stream>>>(
            query, kt, dwb, lnw, lnb, q_act);
    }

    // 2) value GEMM -> padded fp32 layout
    {
        dim3 grid(M / 128, 2);
        gemm_mfma<1><<<grid, 256, 0, stream>>>(q_act, wt_val, bval, v_pad, 256);
    }
    // 3) fused off+attn GEMM (N=128)
    {
        dim3 grid(M / 128, 1);
        gemm_mfma<0><<<grid, 256, 0, stream>>>(q_act, wt_oa, b_oa, oa, 128);
    }
    // 4) sampling + weighted sum -> bf16
    sampler_kernel<<<M / 4, 256, 0, stream>>>(rp, oa, v_pad, out_attn);

    // 5) output GEMM -> d_out fp32
    {
        dim3 grid(M / 128, 2);
        gemm_mfma<0><<<grid, 256, 0, stream>>>(out_attn, wt_out, bout, out, 256);
    }
}

// Round 6
// 113.816 us; speedup vs baseline: 10.6990x; 1.2003x over previous
//
#include <hip/hip_runtime.h>
#include <hip/hip_bf16.h>
#include <math.h>

// Problem constants
#define NB   2
#define CC   256
#define HH   128
#define WW   128
#define HPP  130
#define WPP  130
#define LQ   16384   // HH*WW

typedef __attribute__((ext_vector_type(8))) short short8;
typedef __attribute__((ext_vector_type(4))) float f32x4;
typedef __attribute__((ext_vector_type(4))) unsigned int u32x4;

static __device__ __forceinline__ unsigned short f2bf(float f) {
    __hip_bfloat16 h = __float2bfloat16(f);
    return __builtin_bit_cast(unsigned short, h);
}

// branch-free tanh-form GELU: x * sigmoid(1.5957691*(x + 0.044715 x^3))
static __device__ __forceinline__ float gelu_fast(float x) {
    float u = x * x;
    float t = x * fmaf(0.044715f, u, 1.0f);
    // e = exp(1.5957691216*t) = exp2(t * 2.3022083)
    float e = __builtin_amdgcn_exp2f(t * 2.3022083f);
    float r = __builtin_amdgcn_rcpf(e + 1.0f);
    return x - x * r;   // x * (1 - 1/(1+e)) = x * sigmoid(...)
}

// -------------------------------------------------------------------------
// Kernel A: merged weight prep.
// blocks 0..48    : kt[k][c]      = dwk[c][k]                (fp32)
// blocks 49..304  : wt_val[n][k]  = bf16(Wval[k][n])
// blocks 305..560 : wt_out[n][k]  = bf16(Wout[k][n])
// blocks 561..816 : wt_oa[n][k]   = bf16(fused Woff/Wattn), b_oa
// -------------------------------------------------------------------------
__global__ __launch_bounds__(256) void prep_kernel(
    const float* __restrict__ dwk,
    const float* __restrict__ Wval,
    const float* __restrict__ Wout,
    const float* __restrict__ Woff, const float* __restrict__ boff,
    const float* __restrict__ Wattn, const float* __restrict__ battn,
    float* __restrict__ kt,
    unsigned short* __restrict__ wt_val,
    unsigned short* __restrict__ wt_out,
    unsigned short* __restrict__ wt_oa,
    float* __restrict__ b_oa)
{
    int b = blockIdx.x;
    int t = threadIdx.x;
    if (b < 49) {
        kt[b * CC + t] = dwk[t * 49 + b];
    } else if (b < 305) {
        int k = b - 49;
        wt_val[(size_t)t * 256 + k] = f2bf(Wval[(size_t)k * 256 + t]);
    } else if (b < 561) {
        int k = b - 305;
        wt_out[(size_t)t * 256 + k] = f2bf(Wout[(size_t)k * 256 + t]);
    } else {
        int k = b - 561;
        if (t < 128) {
            float v = 0.f, bb = 0.f;
            if (t < 64)      { v = Woff[(size_t)k * 64 + t];        bb = boff[t]; }
            else if (t < 96) { v = Wattn[(size_t)k * 32 + (t - 64)]; bb = battn[t - 64]; }
            wt_oa[(size_t)t * 256 + k] = f2bf(v);
            if (k == 0) b_oa[t] = bb;
        }
    }
}

// -------------------------------------------------------------------------
// Kernel B: zero only the border of v_pad (interior overwritten by GEMM)
// 516 border positions per n; grid = 2*516 blocks, 256 threads = channels
// -------------------------------------------------------------------------
__global__ __launch_bounds__(256) void zero_border_kernel(float* __restrict__ vpad)
{
    int b = blockIdx.x;
    int n = (b >= 516) ? 1 : 0;
    int i = b - n * 516;
    int y, x;
    if (i < 130)      { y = 0;           x = i; }
    else if (i < 260) { y = 129;         x = i - 130; }
    else if (i < 388) { y = i - 260 + 1; x = 0; }
    else              { y = i - 388 + 1; x = 129; }
    vpad[(((size_t)n * HPP + y) * WPP + x) * CC + threadIdx.x] = 0.f;
}

// -------------------------------------------------------------------------
// Kernel 1: fused depthwise 7x7 conv + bias + channel-LN + GELU -> bf16
// Interior blocks take a check-free path (83% of blocks).
// -------------------------------------------------------------------------
__global__ __launch_bounds__(256) void conv_ln_gelu_kernel(
    const float* __restrict__ q,      // (N, LQ, C)
    const float* __restrict__ kt,     // (49, C)
    const float* __restrict__ kbias,
    const float* __restrict__ lnw,
    const float* __restrict__ lnb,
    unsigned short* __restrict__ qact) // (N, LQ, C) bf16
{
    int c  = threadIdx.x;
    int w0 = blockIdx.x * 8;
    int h  = blockIdx.y;
    int n  = blockIdx.z;

    const float* qn = q + (size_t)n * LQ * CC + c;

    float bias = kbias[c];
    float acc[8];
    #pragma unroll
    for (int i = 0; i < 8; ++i) acc[i] = bias;

    if (w0 >= 8 && w0 <= 112 && h >= 3 && h <= 124) {
        // -------- interior: no bounds checks --------
        #pragma unroll
        for (int ky = 0; ky < 7; ++ky) {
            const float* qrow = qn + ((size_t)(h + ky - 3) * WW + (w0 - 3)) * CC;
            float wt[7];
            #pragma unroll
            for (int kx = 0; kx < 7; ++kx)
                wt[kx] = kt[(ky * 7 + kx) * CC + c];
            float in[14];
            #pragma unroll
            for (int j = 0; j < 14; ++j)
                in[j] = qrow[(size_t)j * CC];
            #pragma unroll
            for (int i = 0; i < 8; ++i)
                #pragma unroll
                for (int kx = 0; kx < 7; ++kx)
                    acc[i] = fmaf(in[i + kx], wt[kx], acc[i]);
        }
    } else {
        // -------- border: checked --------
        #pragma unroll
        for (int ky = 0; ky < 7; ++ky) {
            int iy = h + ky - 3;
            if (iy < 0 || iy >= HH) continue;
            float wt[7];
            #pragma unroll
            for (int kx = 0; kx < 7; ++kx)
                wt[kx] = kt[(ky * 7 + kx) * CC + c];
            float in[14];
            const float* qrow = qn + (size_t)iy * WW * CC;
            #pragma unroll
            for (int j = 0; j < 14; ++j) {
                int ix = w0 - 3 + j;
                in[j] = (ix >= 0 && ix < WW) ? qrow[(size_t)ix * CC] : 0.f;
            }
            #pragma unroll
            for (int i = 0; i < 8; ++i)
                #pragma unroll
                for (int kx = 0; kx < 7; ++kx)
                    acc[i] = fmaf(in[i + kx], wt[kx], acc[i]);
        }
    }

    // LayerNorm across 256 channels for each of 8 positions
    __shared__ float lsum[8][4];
    __shared__ float lsq[8][4];
    int lane = threadIdx.x & 63;
    int wv   = threadIdx.x >> 6;

    #pragma unroll
    for (int i = 0; i < 8; ++i) {
        float v  = acc[i];
        float v2 = v * v;
        #pragma unroll
        for (int m = 1; m < 64; m <<= 1) {
            v  += __shfl_xor(v,  m);
            v2 += __shfl_xor(v2, m);
        }
        if (lane == 0) { lsum[i][wv] = v; lsq[i][wv] = v2; }
    }
    __syncthreads();

    float lw = lnw[c];
    float lb = lnb[c];
    unsigned short* qo = qact + (((size_t)n * LQ) + (size_t)h * WW + w0) * CC + c;

    #pragma unroll
    for (int i = 0; i < 8; ++i) {
        float s  = lsum[i][0] + lsum[i][1] + lsum[i][2] + lsum[i][3];
        float s2 = lsq[i][0]  + lsq[i][1]  + lsq[i][2]  + lsq[i][3];
        float mu  = s * (1.0f / 256.0f);
        float var = s2 * (1.0f / 256.0f) - mu * mu;
        float inv = rsqrtf(var + 1e-5f);
        float yv  = (acc[i] - mu) * inv * lw + lb;
        qo[(size_t)i * CC] = f2bf(gelu_fast(yv));
    }
}

// -------------------------------------------------------------------------
// Kernel 2a: merged value + oa GEMM (bf16 MFMA), grid.y: 0,1=val  2=oa
// value: C(f32, padded layout) = A * wt_val^T + bval
// oa   : C(f32, row-major 128) = A * wt_oa^T  + b_oa
// -------------------------------------------------------------------------
__global__ __launch_bounds__(256) void gemm_val_oa(
    const unsigned short* __restrict__ A,
    const unsigned short* __restrict__ Bv, const float* __restrict__ bv_,
    float* __restrict__ Cv,
    const unsigned short* __restrict__ Bo, const float* __restrict__ bo_,
    float* __restrict__ Co)
{
    __shared__ unsigned short Al[128][72];
    __shared__ unsigned short Bl[128][72];

    bool oam = (blockIdx.y == 2);
    const unsigned short* Bt = oam ? Bo : Bv;
    const float* bias = oam ? bo_ : bv_;
    int bn = oam ? 0 : blockIdx.y * 128;

    int t    = threadIdx.x;
    int bm   = blockIdx.x * 128;
    int wid  = t >> 6;
    int lane = t & 63;
    int wr   = wid >> 1;
    int wc   = wid & 1;
    int lr   = lane & 15;
    int lg   = lane >> 4;

    int srow = t >> 1;
    int sseg = (t & 1) << 5;

    const unsigned short* gA = A + (size_t)(bm + srow) * 256 + sseg;
    const unsigned short* gB = Bt + (size_t)(bn + srow) * 256 + sseg;
    unsigned short* lA = &Al[srow][sseg];
    unsigned short* lB = &Bl[srow][sseg];

    f32x4 acc[4][4] = {};

    for (int kt = 0; kt < 4; ++kt) {
        const unsigned short* ga = gA + kt * 64;
        const unsigned short* gb = gB + kt * 64;
        u32x4 a0 = *(const u32x4*)(ga);
        u32x4 a1 = *(const u32x4*)(ga + 8);
        u32x4 a2 = *(const u32x4*)(ga + 16);
        u32x4 a3 = *(const u32x4*)(ga + 24);
        u32x4 b0 = *(const u32x4*)(gb);
        u32x4 b1 = *(const u32x4*)(gb + 8);
        u32x4 b2 = *(const u32x4*)(gb + 16);
        u32x4 b3 = *(const u32x4*)(gb + 24);
        *(u32x4*)(lA)      = a0;
        *(u32x4*)(lA + 8)  = a1;
        *(u32x4*)(lA + 16) = a2;
        *(u32x4*)(lA + 24) = a3;
        *(u32x4*)(lB)      = b0;
        *(u32x4*)(lB + 8)  = b1;
        *(u32x4*)(lB + 16) = b2;
        *(u32x4*)(lB + 24) = b3;
        __syncthreads();

        #pragma unroll
        for (int kk = 0; kk < 2; ++kk) {
            short8 af[4], bfr[4];
            #pragma unroll
            for (int m = 0; m < 4; ++m)
                af[m] = *(const short8*)(&Al[wr * 64 + m * 16 + lr][kk * 32 + lg * 8]);
            #pragma unroll
            for (int nn = 0; nn < 4; ++nn)
                bfr[nn] = *(const short8*)(&Bl[wc * 64 + nn * 16 + lr][kk * 32 + lg * 8]);
            #pragma unroll
            for (int m = 0; m < 4; ++m)
                #pragma unroll
                for (int nn = 0; nn < 4; ++nn)
                    acc[m][nn] = __builtin_amdgcn_mfma_f32_16x16x32_bf16(
                        af[m], bfr[nn], acc[m][nn], 0, 0, 0);
        }
        __syncthreads();
    }

    float bvv[4];
    #pragma unroll
    for (int nn = 0; nn < 4; ++nn) bvv[nn] = bias[bn + wc * 64 + nn * 16 + lr];

    #pragma unroll
    for (int m = 0; m < 4; ++m) {
        #pragma unroll
        for (int j = 0; j < 4; ++j) {
            int row = bm + wr * 64 + m * 16 + lg * 4 + j;
            size_t rbase;
            if (oam) {
                rbase = (size_t)row * 128;
            } else {
                int nb = row >> 14;
                int hw = row & 16383;
                int hh = hw >> 7;
                int ww = hw & 127;
                rbase = (((size_t)nb * HPP + (hh + 1)) * WPP + (ww + 1)) * CC;
            }
            float* C = oam ? Co : Cv;
            #pragma unroll
            for (int nn = 0; nn < 4; ++nn) {
                int col = bn + wc * 64 + nn * 16 + lr;
                C[rbase + col] = acc[m][nn][j] + bvv[nn];
            }
        }
    }
}

// -------------------------------------------------------------------------
// Kernel 2b: bf16 MFMA GEMM, row-major store (output GEMM)
// -------------------------------------------------------------------------
__global__ __launch_bounds__(256) void gemm_mfma_row(
    const unsigned short* __restrict__ A,
    const unsigned short* __restrict__ Bt,
    const float* __restrict__ bias,
    float* __restrict__ C,
    int Nn)
{
    __shared__ unsigned short Al[128][72];
    __shared__ unsigned short Bl[128][72];

    int t    = threadIdx.x;
    int bm   = blockIdx.x * 128;
    int bn   = blockIdx.y * 128;
    int wid  = t >> 6;
    int lane = t & 63;
    int wr   = wid >> 1;
    int wc   = wid & 1;
    int lr   = lane & 15;
    int lg   = lane >> 4;

    int srow = t >> 1;
    int sseg = (t & 1) << 5;

    const unsigned short* gA = A + (size_t)(bm + srow) * 256 + sseg;
    const unsigned short* gB = Bt + (size_t)(bn + srow) * 256 + sseg;
    unsigned short* lA = &Al[srow][sseg];
    unsigned short* lB = &Bl[srow][sseg];

    f32x4 acc[4][4] = {};

    for (int kt = 0; kt < 4; ++kt) {
        const unsigned short* ga = gA + kt * 64;
        const unsigned short* gb = gB + kt * 64;
        u32x4 a0 = *(const u32x4*)(ga);
        u32x4 a1 = *(const u32x4*)(ga + 8);
        u32x4 a2 = *(const u32x4*)(ga + 16);
        u32x4 a3 = *(const u32x4*)(ga + 24);
        u32x4 b0 = *(const u32x4*)(gb);
        u32x4 b1 = *(const u32x4*)(gb + 8);
        u32x4 b2 = *(const u32x4*)(gb + 16);
        u32x4 b3 = *(const u32x4*)(gb + 24);
        *(u32x4*)(lA)      = a0;
        *(u32x4*)(lA + 8)  = a1;
        *(u32x4*)(lA + 16) = a2;
        *(u32x4*)(lA + 24) = a3;
        *(u32x4*)(lB)      = b0;
        *(u32x4*)(lB + 8)  = b1;
        *(u32x4*)(lB + 16) = b2;
        *(u32x4*)(lB + 24) = b3;
        __syncthreads();

        #pragma unroll
        for (int kk = 0; kk < 2; ++kk) {
            short8 af[4], bfr[4];
            #pragma unroll
            for (int m = 0; m < 4; ++m)
                af[m] = *(const short8*)(&Al[wr * 64 + m * 16 + lr][kk * 32 + lg * 8]);
            #pragma unroll
            for (int nn = 0; nn < 4; ++nn)
                bfr[nn] = *(const short8*)(&Bl[wc * 64 + nn * 16 + lr][kk * 32 + lg * 8]);
            #pragma unroll
            for (int m = 0; m < 4; ++m)
                #pragma unroll
                for (int nn = 0; nn < 4; ++nn)
                    acc[m][nn] = __builtin_amdgcn_mfma_f32_16x16x32_bf16(
                        af[m], bfr[nn], acc[m][nn], 0, 0, 0);
        }
        __syncthreads();
    }

    float bvv[4];
    #pragma unroll
    for (int nn = 0; nn < 4; ++nn) bvv[nn] = bias[bn + wc * 64 + nn * 16 + lr];

    #pragma unroll
    for (int m = 0; m < 4; ++m) {
        #pragma unroll
        for (int j = 0; j < 4; ++j) {
            int row = bm + wr * 64 + m * 16 + lg * 4 + j;
            size_t rbase = (size_t)row * Nn;
            #pragma unroll
            for (int nn = 0; nn < 4; ++nn) {
                int col = bn + wc * 64 + nn * 16 + lr;
                C[rbase + col] = acc[m][nn][j] + bvv[nn];
            }
        }
    }
}

// -------------------------------------------------------------------------
// Kernel 3: deformable bilinear sampling + attention-weighted sum
// -------------------------------------------------------------------------
__global__ __launch_bounds__(256) void sampler_kernel(
    const float* __restrict__ rp,     // (N, LQ, 1, 2)
    const float* __restrict__ oa,     // (N*LQ, 128)
    const float* __restrict__ vpad,   // (N, HP, WP, C)
    unsigned short* __restrict__ outb) // (N*LQ, C) bf16
{
    __shared__ int4   sIdx[4][4][8];
    __shared__ float4 sW[4][4][8];

    int tid  = threadIdx.x;
    int row0 = blockIdx.x * 4;

    if (tid < 128) {
        int rl   = tid >> 5;
        int hp   = tid & 31;
        int head = hp >> 2;
        int p    = hp & 3;
        int row  = row0 + rl;

        float ref0 = rp[(size_t)row * 2 + 0];
        float ref1 = rp[(size_t)row * 2 + 1];
        float o0 = oa[(size_t)row * 128 + head * 8 + p * 2 + 0];
        float o1 = oa[(size_t)row * 128 + head * 8 + p * 2 + 1];
        float al = oa[(size_t)row * 128 + 64 + head * 4 + p];
        float a  = 1.0f / (1.0f + __builtin_amdgcn_exp2f(-al * 1.4426950409f));

        float gy = (float)(p >> 1);
        float gx = (float)(p & 1);
        float x = ref0 * WPP + gy + o0 - 0.5f;
        float y = ref1 * HPP + gx + o1 - 0.5f;

        float x0f = floorf(x), y0f = floorf(y);
        int   x0  = (int)x0f,  y0  = (int)y0f;
        float wx1 = x - x0f, wx0 = 1.f - wx1;
        float wy1 = y - y0f, wy0 = 1.f - wy1;
        int x1 = x0 + 1, y1 = y0 + 1;

        bool vx0 = (x0 >= 0) & (x0 < WPP);
        bool vx1 = (x1 >= 0) & (x1 < WPP);
        bool vy0 = (y0 >= 0) & (y0 < HPP);
        bool vy1 = (y1 >= 0) & (y1 < HPP);
        int cx0 = min(max(x0, 0), WPP - 1);
        int cx1 = min(max(x1, 0), WPP - 1);
        int cy0 = min(max(y0, 0), HPP - 1);
        int cy1 = min(max(y1, 0), HPP - 1);

        int4 id;
        id.x = cy0 * WPP + cx0;
        id.y = cy0 * WPP + cx1;
        id.z = cy1 * WPP + cx0;
        id.w = cy1 * WPP + cx1;
        float4 w;
        w.x = (vx0 && vy0) ? a * wx0 * wy0 : 0.f;
        w.y = (vx1 && vy0) ? a * wx1 * wy0 : 0.f;
        w.z = (vx0 && vy1) ? a * wx0 * wy1 : 0.f;
        w.w = (vx1 && vy1) ? a * wx1 * wy1 : 0.f;

        sIdx[rl][p][head] = id;
        sW[rl][p][head]   = w;
    }
    __syncthreads();

    int rl   = tid >> 6;
    int c0   = (tid & 63) * 4;
    int head = c0 >> 5;
    int row  = row0 + rl;
    int n    = row >> 14;
    const float* vbase = vpad + (size_t)n * HPP * WPP * CC + c0;

    float4 acc = make_float4(0.f, 0.f, 0.f, 0.f);
    #pragma unroll
    for (int p = 0; p < 4; ++p) {
        int4   id = sIdx[rl][p][head];
        float4 w  = sW[rl][p][head];
        float4 g0 = *reinterpret_cast<const float4*>(vbase + (size_t)id.x * CC);
        float4 g1 = *reinterpret_cast<const float4*>(vbase + (size_t)id.y * CC);
        float4 g2 = *reinterpret_cast<const float4*>(vbase + (size_t)id.z * CC);
        float4 g3 = *reinterpret_cast<const float4*>(vbase + (size_t)id.w * CC);
        acc.x += w.x * g0.x + w.y * g1.x + w.z * g2.x + w.w * g3.x;
        acc.y += w.x * g0.y + w.y * g1.y + w.z * g2.y + w.w * g3.y;
        acc.z += w.x * g0.z + w.y * g1.z + w.z * g2.z + w.w * g3.z;
        acc.w += w.x * g0.w + w.y * g1.w + w.z * g2.w + w.w * g3.w;
    }
    ushort4 o;
    o.x = f2bf(acc.x);
    o.y = f2bf(acc.y);
    o.z = f2bf(acc.z);
    o.w = f2bf(acc.w);
    *reinterpret_cast<ushort4*>(&outb[(size_t)row * CC + c0]) = o;
}

// -------------------------------------------------------------------------
extern "C" void kernel_launch(void* const* d_in, const int* in_sizes, int n_in,
                              void* d_out, int out_size, void* d_ws, size_t ws_size,
                              hipStream_t stream)
{
    const float* query = (const float*)d_in[0];
    const float* rp    = (const float*)d_in[1];
    const float* dwk   = (const float*)d_in[4];
    const float* dwb   = (const float*)d_in[5];
    const float* lnw   = (const float*)d_in[6];
    const float* lnb   = (const float*)d_in[7];
    const float* Woff  = (const float*)d_in[8];
    const float* boff  = (const float*)d_in[9];
    const float* Wattn = (const float*)d_in[10];
    const float* battn = (const float*)d_in[11];
    const float* Wval  = (const float*)d_in[12];
    const float* bval  = (const float*)d_in[13];
    const float* Wout  = (const float*)d_in[14];
    const float* bout  = (const float*)d_in[15];
    float* out = (float*)d_out;

    const int M = NB * LQ;  // 32768

    // workspace layout (bytes)
    uint8_t* w8 = (uint8_t*)d_ws;
    unsigned short* q_act  = (unsigned short*)w8;                    // 16,777,216
    float*          v_pad  = (float*)(w8 + 16777216);                // 34,611,200
    float*          oa     = (float*)(w8 + 51388416);                // 16,777,216
    unsigned short* wt_val = (unsigned short*)(w8 + 68165632);       //    131,072
    unsigned short* wt_out = (unsigned short*)(w8 + 68296704);       //    131,072
    unsigned short* wt_oa  = (unsigned short*)(w8 + 68427776);       //     65,536
    float*          b_oa   = (float*)(w8 + 68493312);                //        512
    float*          kt     = (float*)(w8 + 68493824);                //     50,176
    unsigned short* out_attn = q_act;  // alias: q_act dead after oa GEMM

    // border-only zeroing of v_pad (interior fully written by value GEMM)
    zero_border_kernel<<<1032, 256, 0, stream>>>(v_pad);

    // merged weight prep
    prep_kernel<<<817, 256, 0, stream>>>(
        dwk, Wval, Wout, Woff, boff, Wattn, battn,
        kt, wt_val, wt_out, wt_oa, b_oa);

    // conv + LN + GELU -> bf16 q_act
    {
        dim3 grid(WW / 8, HH, NB);
        conv_ln_gelu_kernel<<<grid, 256, 0, stream>>>(
            query, kt, dwb, lnw, lnb, q_act);
    }

    // value GEMM (padded layout) + oa GEMM, one launch
    {
        dim3 grid(M / 128, 3);
        gemm_val_oa<<<grid, 256, 0, stream>>>(
            q_act, wt_val, bval, v_pad, wt_oa, b_oa, oa);
    }

    // sampling + weighted sum -> bf16
    sampler_kernel<<<M / 4, 256, 0, stream>>>(rp, oa, v_pad, out_attn);

    // output GEMM -> d_out fp32
    {
        dim3 grid(M / 128, 2);
        gemm_mfma_row<<<grid, 256, 0, stream>>>(out_attn, wt_out, bout, out, 256);
    }
}